// Round 9
// baseline (110.054 us; speedup 1.0000x reference)
//
#include <hip/hip_runtime.h>

#define NPROP 8192
#define NT 1024
typedef unsigned long long u64;

__device__ __forceinline__ int bucket_of(float s) {
    int b = (int)(s * 8192.0f);   // exact: *2^13 is an exponent shift
    return b < 0 ? 0 : (b > NPROP - 1 ? NPROP - 1 : b);
}

__device__ __forceinline__ bool iou_gt_thr(float4 a, float4 b) {
    float areaA = (a.z - a.x) * (a.w - a.y);
    float areaB = (b.z - b.x) * (b.w - b.y);
    float lx = fmaxf(a.x, b.x), ly = fmaxf(a.y, b.y);
    float rx = fminf(a.z, b.z), ry = fminf(a.w, b.w);
    float w = fmaxf(rx - lx, 0.0f), h = fmaxf(ry - ly, 0.0f);
    float inter = w * h;
    float uni = areaA + areaB - inter;
    float iou = inter / fmaxf(uni, 1e-6f);
    return iou > 0.3f;
}

// K0: zero the histogram (replaces the 39us fillBufferAligned)
__global__ void k_zero(int* __restrict__ hist) {
    hist[blockIdx.x * NT + threadIdx.x] = 0;
}

// K1: bucket histogram
__global__ void k_hist(const float* __restrict__ scores, int* __restrict__ hist) {
    int i = blockIdx.x * blockDim.x + threadIdx.x;
    if (i < NPROP) atomicAdd(&hist[bucket_of(scores[i])], 1);
}

// K2: exclusive prefix over 8192 bucket counts
__global__ __launch_bounds__(NT)
void k_scan(const int* __restrict__ hist, int* __restrict__ pref_ex,
            int* __restrict__ pref_mut) {
    __shared__ int wsum[16], wexcl[16];
    int tid = threadIdx.x, lane = tid & 63, wave = tid >> 6;
    int h[8]; int tot = 0;
    #pragma unroll
    for (int u = 0; u < 8; u++) { h[u] = hist[tid * 8 + u]; tot += h[u]; }
    int incl = tot;
    #pragma unroll
    for (int off = 1; off < 64; off <<= 1) {
        int n = __shfl_up(incl, off, 64);
        if (lane >= off) incl += n;
    }
    if (lane == 63) wsum[wave] = incl;
    __syncthreads();
    if (tid == 0) {
        int acc = 0;
        #pragma unroll
        for (int w = 0; w < 16; w++) { int t = wsum[w]; wexcl[w] = acc; acc += t; }
    }
    __syncthreads();
    int run = wexcl[wave] + (incl - tot);
    #pragma unroll
    for (int u = 0; u < 8; u++) {
        pref_ex[tid * 8 + u] = run;
        pref_mut[tid * 8 + u] = run;
        run += h[u];
    }
}

// K3: scatter into bucket-grouped order
__global__ void k_scatter(const float* __restrict__ scores, int* __restrict__ pref_mut,
                          int* __restrict__ tmp_idx) {
    int i = blockIdx.x * blockDim.x + threadIdx.x;
    if (i < NPROP) {
        int slot = atomicAdd(&pref_mut[bucket_of(scores[i])], 1);
        tmp_idx[slot] = i;
    }
}

// K4: exact stable rank via in-bucket counting + validity
__global__ void k_rank(const float* __restrict__ scores, const float* __restrict__ boxes,
                       const float* __restrict__ img,
                       const int* __restrict__ tmp_idx, const int* __restrict__ pref_ex,
                       const int* __restrict__ pref_mut,
                       float4* __restrict__ srt_box, float* __restrict__ srt_sv) {
    int p = blockIdx.x * blockDim.x + threadIdx.x;
    if (p >= NPROP) return;
    int i = tmp_idx[p];
    float s = scores[i];
    u64 key = ((u64)__float_as_uint(s) << 32) | (u64)(unsigned)(NPROP - 1 - i);
    int b = bucket_of(s);
    int lo = pref_ex[b], hi = pref_mut[b];
    int cnt = 0;
    for (int q = lo; q < hi; q++) {
        int j = tmp_idx[q];
        u64 kj = ((u64)__float_as_uint(scores[j]) << 32) | (u64)(unsigned)(NPROP - 1 - j);
        cnt += (kj < key) ? 1 : 0;
    }
    int rank = NPROP - 1 - (lo + cnt);
    float4 bx = reinterpret_cast<const float4*>(boxes)[i];
    float ix1 = img[0], iy1 = img[1], ix2 = img[2], iy2 = img[3];
    float img_area = (ix2 - ix1) * (iy2 - iy1);
    float w = bx.z - bx.x, hh = bx.w - bx.y;
    float ratio = w / (hh + 1e-12f);
    bool vs = (ratio > 0.25f) && (ratio < 4.0f);
    float lx = fmaxf(ix1, bx.x), ly = fmaxf(iy1, bx.y);
    float rx = fminf(ix2, bx.z), ry = fminf(iy2, bx.w);
    float iw = fmaxf(rx - lx, 0.0f), ih = fmaxf(ry - ly, 0.0f);
    float iof = (iw * ih) / fmaxf(img_area, 1e-6f);
    bool vf = vs && (iof > 0.01f) && (s > 0.85f);
    srt_box[rank] = bx;
    srt_sv[rank] = __uint_as_float(__float_as_uint(s) | (vf ? 0x80000000u : 0u));
}

// K5: compact valid subset (scan over sorted order) + V/W meta
__global__ __launch_bounds__(NT)
void k_compact(const float4* __restrict__ srt_box, const float* __restrict__ srt_sv,
               float4* __restrict__ cbox, int* __restrict__ crank,
               int* __restrict__ meta) {
    __shared__ int wsum[16], wexcl[16];
    const int tid = threadIdx.x, lane = tid & 63, wave = tid >> 6;
    bool vf[8]; int tot = 0;
    float4 bx[8];
    #pragma unroll
    for (int u = 0; u < 8; u++) {
        int p = tid * 8 + u;
        bx[u] = srt_box[p];
        vf[u] = (__float_as_uint(srt_sv[p]) >> 31) != 0;
        tot += vf[u] ? 1 : 0;
    }
    int incl = tot;
    #pragma unroll
    for (int off = 1; off < 64; off <<= 1) {
        int n = __shfl_up(incl, off, 64);
        if (lane >= off) incl += n;
    }
    if (lane == 63) wsum[wave] = incl;
    __syncthreads();
    if (tid == 0) {
        int acc = 0;
        #pragma unroll
        for (int w = 0; w < 16; w++) { int t = wsum[w]; wexcl[w] = acc; acc += t; }
        int V = acc == 0 ? 1 : acc;
        meta[0] = V;
        meta[1] = (V + 63) >> 6;
        meta[2] = acc;              // raw count (0 => fallback)
    }
    __syncthreads();
    int base = wexcl[wave] + (incl - tot);
    #pragma unroll
    for (int u = 0; u < 8; u++) {
        int p = tid * 8 + u;
        if (vf[u]) { crank[p] = base; cbox[base] = bx[u]; base++; }
        else crank[p] = -1;
    }
    if (meta[2] == 0 && tid == 0) { crank[0] = 0; cbox[0] = srt_box[0]; }
}

// K6: suppression mask matrix + contiguous diagonal-word array
__global__ __launch_bounds__(256)
void k_mask(const float4* __restrict__ cbox, const int* __restrict__ meta,
            u64* __restrict__ mask, u64* __restrict__ diagM) {
    const int V = meta[0], W = meta[1];
    const int lane = threadIdx.x & 63;
    int gw = blockIdx.x * 4 + (threadIdx.x >> 6);
    for (int r = gw; r < V; r += 1024) {
        float4 br = cbox[r];
        for (int w = (r >> 6); w < W; w++) {
            int col = w * 64 + lane;
            bool ok = (col < V) && (col > r) && iou_gt_thr(br, cbox[col]);
            u64 bal = __ballot(ok);
            if (lane == 0) {
                mask[(u64)r * W + w] = bal;
                if (w == (r >> 6)) diagM[r] = bal;
            }
        }
    }
}

// K7: greedy resolve (scalar SALU chain, 1 barrier/block) + fused output
__global__ __launch_bounds__(NT)
void k_resolve_out(const u64* __restrict__ mask, const u64* __restrict__ diagM,
                   const int* __restrict__ meta,
                   const float4* __restrict__ srt_box, const float* __restrict__ srt_sv,
                   const int* __restrict__ crank, float* __restrict__ out) {
    __shared__ u64 rem[NPROP / 64];
    const int V = meta[0], W = meta[1];
    const int tid = threadIdx.x, lane = tid & 63, wave = tid >> 6;

    for (int w = tid; w < NPROP / 64; w += NT) {
        int b0 = w * 64; u64 m;
        if (b0 >= V) m = ~0ull;
        else if (b0 + 64 <= V) m = 0ull;
        else m = (~0ull) << (V - b0);
        rem[w] = m;
    }
    __syncthreads();

    for (int b = 0; b < W; b++) {
        const int rb0 = b * 64;
        // per-lane diag word; rows >= V may be garbage but their rem-bit is
        // pre-set so the chain never consumes them.
        u64 d = diagM[rb0 + lane];
        int d_lo = (int)(unsigned)(d & 0xffffffffull);
        int d_hi = (int)(unsigned)(d >> 32);
        // uniform running removed-word in SGPRs -> SALU dependency chain
        u64 rb_ld = rem[b];
        unsigned r_lo = (unsigned)__builtin_amdgcn_readfirstlane((int)(unsigned)(rb_ld & 0xffffffffull));
        unsigned r_hi = (unsigned)__builtin_amdgcn_readfirstlane((int)(unsigned)(rb_ld >> 32));
        u64 r = ((u64)r_hi << 32) | (u64)r_lo;
        #pragma unroll
        for (int i = 0; i < 64; i++) {
            unsigned dl = (unsigned)__builtin_amdgcn_readlane(d_lo, i);
            unsigned dh = (unsigned)__builtin_amdgcn_readlane(d_hi, i);
            u64 di = ((u64)dh << 32) | (u64)dl;
            if (!((r >> i) & 1ull)) r |= di;
        }
        if (tid == 0) rem[b] = r;   // benign same-value race (chain idempotent)
        // apply: every wave already holds r -> start immediately, no barrier
        u64 keptm = ~r;
        #pragma unroll
        for (int t = 0; t < 4; t++) {
            int rl = wave * 4 + t;
            int row = rb0 + rl;
            if (row < V && ((keptm >> rl) & 1ull)) {
                for (int w2 = b + 1 + lane; w2 < W; w2 += 64) {
                    u64 m = mask[(u64)row * W + w2];
                    if (m) atomicOr((unsigned long long*)&rem[w2], m);
                }
            }
        }
        __syncthreads();
    }

    // fused final output: [N,5]*keep + keep mask, vectorized stores
    float ob[40]; float om[8];
    #pragma unroll
    for (int u = 0; u < 8; u++) {
        int p = tid * 8 + u;
        float4 b = srt_box[p];
        unsigned svb = __float_as_uint(srt_sv[p]);
        float s = __uint_as_float(svb & 0x7fffffffu);
        int kk = crank[p];
        bool keep = (kk >= 0) && !((rem[kk >> 6] >> (kk & 63)) & 1ull);
        float m = keep ? 1.0f : 0.0f;
        ob[u * 5 + 0] = b.x * m;
        ob[u * 5 + 1] = b.y * m;
        ob[u * 5 + 2] = b.z * m;
        ob[u * 5 + 3] = b.w * m;
        ob[u * 5 + 4] = s * m;
        om[u] = m;
    }
    float4* o4 = reinterpret_cast<float4*>(out) + tid * 10;
    #pragma unroll
    for (int q = 0; q < 10; q++)
        o4[q] = make_float4(ob[q * 4 + 0], ob[q * 4 + 1], ob[q * 4 + 2], ob[q * 4 + 3]);
    float4* m4 = reinterpret_cast<float4*>(out + NPROP * 5) + tid * 2;
    m4[0] = make_float4(om[0], om[1], om[2], om[3]);
    m4[1] = make_float4(om[4], om[5], om[6], om[7]);
}

extern "C" void kernel_launch(void* const* d_in, const int* in_sizes, int n_in,
                              void* d_out, int out_size, void* d_ws, size_t ws_size,
                              hipStream_t stream) {
    const float* boxes  = (const float*)d_in[0];
    const float* scores = (const float*)d_in[1];
    const float* img    = (const float*)d_in[2];
    char* ws = (char*)d_ws;
    int*    hist     = (int*)(ws + 0);         // 32 KiB
    int*    pref_ex  = (int*)(ws + 32768);     // 32 KiB
    int*    pref_mut = (int*)(ws + 65536);     // 32 KiB
    int*    tmp_idx  = (int*)(ws + 98304);     // 32 KiB
    float*  srt_sv   = (float*)(ws + 131072);  // 32 KiB
    float4* srt_box  = (float4*)(ws + 163840); // 128 KiB
    float4* cbox     = (float4*)(ws + 294912); // 128 KiB
    int*    crank    = (int*)(ws + 425984);    // 32 KiB
    int*    meta     = (int*)(ws + 458752);    // 1 KiB (padded)
    u64*    diagM    = (u64*)(ws + 459776);    // 64 KiB
    u64*    mask     = (u64*)(ws + 525312);    // V*W*8 B (realistic ~200 KiB)
    float* out = (float*)d_out;

    k_zero<<<8, NT, 0, stream>>>(hist);
    k_hist<<<32, 256, 0, stream>>>(scores, hist);
    k_scan<<<1, NT, 0, stream>>>(hist, pref_ex, pref_mut);
    k_scatter<<<32, 256, 0, stream>>>(scores, pref_mut, tmp_idx);
    k_rank<<<32, 256, 0, stream>>>(scores, boxes, img, tmp_idx, pref_ex, pref_mut,
                                   srt_box, srt_sv);
    k_compact<<<1, NT, 0, stream>>>(srt_box, srt_sv, cbox, crank, meta);
    k_mask<<<256, 256, 0, stream>>>(cbox, meta, mask, diagM);
    k_resolve_out<<<1, NT, 0, stream>>>(mask, diagM, meta, srt_box, srt_sv, crank, out);
}

// Round 10
// 82.059 us; speedup vs baseline: 1.3412x; 1.3412x over previous
//
#include <hip/hip_runtime.h>

#define NPROP 8192
#define NT 1024
#define SLABW 25   // slab capacity (words/row), padded odd to spread LDS banks
typedef unsigned long long u64;

__device__ __forceinline__ int bucket_of(float s) {
    int b = (int)(s * 8192.0f);   // exact: *2^13 is an exponent shift
    return b < 0 ? 0 : (b > NPROP - 1 ? NPROP - 1 : b);
}

__device__ __forceinline__ bool iou_gt_thr(float4 a, float4 b) {
    float areaA = (a.z - a.x) * (a.w - a.y);
    float areaB = (b.z - b.x) * (b.w - b.y);
    float lx = fmaxf(a.x, b.x), ly = fmaxf(a.y, b.y);
    float rx = fminf(a.z, b.z), ry = fminf(a.w, b.w);
    float w = fmaxf(rx - lx, 0.0f), h = fmaxf(ry - ly, 0.0f);
    float inter = w * h;
    float uni = areaA + areaB - inter;
    float iou = inter / fmaxf(uni, 1e-6f);
    return iou > 0.3f;
}

// K1: LDS histogram + exclusive prefix (fuses old k_zero+k_hist+k_scan)
__global__ __launch_bounds__(NT)
void k_scanhist(const float* __restrict__ scores, int* __restrict__ pref_ex,
                int* __restrict__ pref_mut) {
    __shared__ int hist[NPROP];   // 32 KiB
    __shared__ int wsum[16], wexcl[16];
    int tid = threadIdx.x, lane = tid & 63, wave = tid >> 6;
    #pragma unroll
    for (int u = 0; u < 8; u++) hist[tid * 8 + u] = 0;
    __syncthreads();
    const float4* s4 = reinterpret_cast<const float4*>(scores);
    float4 sa = s4[tid * 2], sb = s4[tid * 2 + 1];
    float ss[8] = {sa.x, sa.y, sa.z, sa.w, sb.x, sb.y, sb.z, sb.w};
    #pragma unroll
    for (int u = 0; u < 8; u++) atomicAdd(&hist[bucket_of(ss[u])], 1);
    __syncthreads();
    int h[8]; int tot = 0;
    #pragma unroll
    for (int u = 0; u < 8; u++) { h[u] = hist[tid * 8 + u]; tot += h[u]; }
    int incl = tot;
    #pragma unroll
    for (int off = 1; off < 64; off <<= 1) {
        int n = __shfl_up(incl, off, 64);
        if (lane >= off) incl += n;
    }
    if (lane == 63) wsum[wave] = incl;
    __syncthreads();
    if (tid == 0) {
        int acc = 0;
        #pragma unroll
        for (int w = 0; w < 16; w++) { int t = wsum[w]; wexcl[w] = acc; acc += t; }
    }
    __syncthreads();
    int run = wexcl[wave] + (incl - tot);
    #pragma unroll
    for (int u = 0; u < 8; u++) {
        pref_ex[tid * 8 + u] = run;
        pref_mut[tid * 8 + u] = run;
        run += h[u];
    }
}

// K2: scatter into bucket-grouped order
__global__ void k_scatter(const float* __restrict__ scores, int* __restrict__ pref_mut,
                          int* __restrict__ tmp_idx) {
    int i = blockIdx.x * blockDim.x + threadIdx.x;
    if (i < NPROP) {
        int slot = atomicAdd(&pref_mut[bucket_of(scores[i])], 1);
        tmp_idx[slot] = i;
    }
}

// K3: exact stable rank via in-bucket counting + validity
__global__ void k_rank(const float* __restrict__ scores, const float* __restrict__ boxes,
                       const float* __restrict__ img,
                       const int* __restrict__ tmp_idx, const int* __restrict__ pref_ex,
                       const int* __restrict__ pref_mut,
                       float4* __restrict__ srt_box, float* __restrict__ srt_sv) {
    int p = blockIdx.x * blockDim.x + threadIdx.x;
    if (p >= NPROP) return;
    int i = tmp_idx[p];
    float s = scores[i];
    u64 key = ((u64)__float_as_uint(s) << 32) | (u64)(unsigned)(NPROP - 1 - i);
    int b = bucket_of(s);
    int lo = pref_ex[b], hi = pref_mut[b];
    int cnt = 0;
    for (int q = lo; q < hi; q++) {
        int j = tmp_idx[q];
        u64 kj = ((u64)__float_as_uint(scores[j]) << 32) | (u64)(unsigned)(NPROP - 1 - j);
        cnt += (kj < key) ? 1 : 0;
    }
    int rank = NPROP - 1 - (lo + cnt);
    float4 bx = reinterpret_cast<const float4*>(boxes)[i];
    float ix1 = img[0], iy1 = img[1], ix2 = img[2], iy2 = img[3];
    float img_area = (ix2 - ix1) * (iy2 - iy1);
    float w = bx.z - bx.x, hh = bx.w - bx.y;
    float ratio = w / (hh + 1e-12f);
    bool vs = (ratio > 0.25f) && (ratio < 4.0f);
    float lx = fmaxf(ix1, bx.x), ly = fmaxf(iy1, bx.y);
    float rx = fminf(ix2, bx.z), ry = fminf(iy2, bx.w);
    float iw = fmaxf(rx - lx, 0.0f), ih = fmaxf(ry - ly, 0.0f);
    float iof = (iw * ih) / fmaxf(img_area, 1e-6f);
    bool vf = vs && (iof > 0.01f) && (s > 0.85f);
    srt_box[rank] = bx;
    srt_sv[rank] = __uint_as_float(__float_as_uint(s) | (vf ? 0x80000000u : 0u));
}

// K4: compact valid subset + V/W meta
__global__ __launch_bounds__(NT)
void k_compact(const float4* __restrict__ srt_box, const float* __restrict__ srt_sv,
               float4* __restrict__ cbox, int* __restrict__ crank,
               int* __restrict__ meta) {
    __shared__ int wsum[16], wexcl[16];
    const int tid = threadIdx.x, lane = tid & 63, wave = tid >> 6;
    bool vf[8]; int tot = 0;
    float4 bx[8];
    #pragma unroll
    for (int u = 0; u < 8; u++) {
        int p = tid * 8 + u;
        bx[u] = srt_box[p];
        vf[u] = (__float_as_uint(srt_sv[p]) >> 31) != 0;
        tot += vf[u] ? 1 : 0;
    }
    int incl = tot;
    #pragma unroll
    for (int off = 1; off < 64; off <<= 1) {
        int n = __shfl_up(incl, off, 64);
        if (lane >= off) incl += n;
    }
    if (lane == 63) wsum[wave] = incl;
    __syncthreads();
    if (tid == 0) {
        int acc = 0;
        #pragma unroll
        for (int w = 0; w < 16; w++) { int t = wsum[w]; wexcl[w] = acc; acc += t; }
        int V = acc == 0 ? 1 : acc;
        meta[0] = V;
        meta[1] = (V + 63) >> 6;
        meta[2] = acc;              // raw count (0 => fallback)
    }
    __syncthreads();
    int base = wexcl[wave] + (incl - tot);
    #pragma unroll
    for (int u = 0; u < 8; u++) {
        int p = tid * 8 + u;
        if (vf[u]) { crank[p] = base; cbox[base] = bx[u]; base++; }
        else crank[p] = -1;
    }
    if (meta[2] == 0 && tid == 0) { crank[0] = 0; cbox[0] = srt_box[0]; }
}

// K5: suppression mask matrix — wave per row, lane per column
__global__ __launch_bounds__(256)
void k_mask(const float4* __restrict__ cbox, const int* __restrict__ meta,
            u64* __restrict__ mask) {
    const int V = meta[0], W = meta[1];
    const int lane = threadIdx.x & 63;
    int gw = blockIdx.x * 4 + (threadIdx.x >> 6);
    for (int r = gw; r < V; r += 1024) {
        float4 br = cbox[r];
        for (int w = (r >> 6); w < W; w++) {
            int col = w * 64 + lane;
            bool ok = (col < V) && (col > r) && iou_gt_thr(br, cbox[col]);
            u64 bal = __ballot(ok);
            if (lane == 0) mask[(u64)r * W + w] = bal;
        }
    }
}

// K6: greedy resolve with double-buffered LDS mask slab + fused output
__global__ __launch_bounds__(NT)
void k_resolve_out(const u64* __restrict__ mask, const int* __restrict__ meta,
                   const float4* __restrict__ srt_box, const float* __restrict__ srt_sv,
                   const int* __restrict__ crank, float* __restrict__ out) {
    __shared__ u64 rem[NPROP / 64];            // 1 KiB
    __shared__ u64 slab[2][64 * SLABW];        // 25.6 KiB
    const int V = meta[0], W = meta[1];
    const int tid = threadIdx.x, lane = tid & 63, wave = tid >> 6;

    for (int w = tid; w < NPROP / 64; w += NT) {
        int b0 = w * 64; u64 m;
        if (b0 >= V) m = ~0ull;
        else if (b0 + 64 <= V) m = 0ull;
        else m = (~0ull) << (V - b0);
        rem[w] = m;
    }
    // prologue: slab for block 0 (rows 0..63, words [0, cnt0))
    {
        int cnt0 = min(W, SLABW);
        int total = 64 * cnt0;
        for (int idx = tid; idx < total; idx += NT) {
            int rl = idx / cnt0, off = idx % cnt0;
            slab[0][rl * SLABW + off] = mask[(u64)rl * W + off];
        }
    }
    __syncthreads();

    int cur = 0;
    for (int b = 0; b < W; b++) {
        const int rb0 = b * 64;
        const int cnt = min(W - b, SLABW);
        // 1) issue prefetch for block b+1 (to regs; consumed after apply)
        u64 pf0 = 0, pf1 = 0; int pi0 = -1, pi1 = -1;
        if (b + 1 < W) {
            int B = b + 1;
            int cn = min(W - B, SLABW);
            int total = 64 * cn;
            int idx1 = tid + NT;
            if (tid < total) {
                int rl = tid / cn, off = tid % cn;
                pf0 = mask[(u64)(B * 64 + rl) * W + (B + off)];
                pi0 = rl * SLABW + off;
            }
            if (idx1 < total) {
                int rl = idx1 / cn, off = idx1 % cn;
                pf1 = mask[(u64)(B * 64 + rl) * W + (B + off)];
                pi1 = rl * SLABW + off;
            }
        }
        // 2) chain on wave 0 only (VALU readlane chain; diag from LDS)
        if (tid < 64) {
            u64 d = slab[cur][lane * SLABW];   // diag word of row rb0+lane
            int d_lo = (int)(unsigned)(d & 0xffffffffull);
            int d_hi = (int)(unsigned)(d >> 32);
            u64 r = rem[b];
            #pragma unroll
            for (int i = 0; i < 64; i++) {
                unsigned dl = (unsigned)__builtin_amdgcn_readlane(d_lo, i);
                unsigned dh = (unsigned)__builtin_amdgcn_readlane(d_hi, i);
                u64 di = ((u64)dh << 32) | (u64)dl;
                if (!((r >> i) & 1ull)) r |= di;
            }
            if (lane == 0) rem[b] = r;
        }
        __syncthreads();
        // 3) apply from LDS slab: per-wave register-OR of its 4 rows, 1 atomic/lane
        u64 keptm = ~rem[b];
        if (lane + 1 < cnt) {
            u64 acc = 0;
            #pragma unroll
            for (int t = 0; t < 4; t++) {
                int rl = wave * 4 + t;
                if ((rb0 + rl) < V && ((keptm >> rl) & 1ull))
                    acc |= slab[cur][rl * SLABW + 1 + lane];
            }
            if (acc) atomicOr((unsigned long long*)&rem[b + 1 + lane], acc);
        }
        // beyond-slab fallback (only if W-b > SLABW; not hit for V~1200)
        if (W - b > SLABW) {
            #pragma unroll
            for (int t = 0; t < 4; t++) {
                int rl = wave * 4 + t; int row = rb0 + rl;
                if (row < V && ((keptm >> rl) & 1ull)) {
                    for (int w2 = b + SLABW + lane; w2 < W; w2 += 64) {
                        u64 m = mask[(u64)row * W + w2];
                        if (m) atomicOr((unsigned long long*)&rem[w2], m);
                    }
                }
            }
        }
        // 4) land prefetch into the other slab buffer
        if (pi0 >= 0) slab[cur ^ 1][pi0] = pf0;
        if (pi1 >= 0) slab[cur ^ 1][pi1] = pf1;
        __syncthreads();
        cur ^= 1;
    }

    // fused final output: [N,5]*keep + keep mask, vectorized stores
    float ob[40]; float om[8];
    #pragma unroll
    for (int u = 0; u < 8; u++) {
        int p = tid * 8 + u;
        float4 b = srt_box[p];
        unsigned svb = __float_as_uint(srt_sv[p]);
        float s = __uint_as_float(svb & 0x7fffffffu);
        int kk = crank[p];
        bool keep = (kk >= 0) && !((rem[kk >> 6] >> (kk & 63)) & 1ull);
        float m = keep ? 1.0f : 0.0f;
        ob[u * 5 + 0] = b.x * m;
        ob[u * 5 + 1] = b.y * m;
        ob[u * 5 + 2] = b.z * m;
        ob[u * 5 + 3] = b.w * m;
        ob[u * 5 + 4] = s * m;
        om[u] = m;
    }
    float4* o4 = reinterpret_cast<float4*>(out) + tid * 10;
    #pragma unroll
    for (int q = 0; q < 10; q++)
        o4[q] = make_float4(ob[q * 4 + 0], ob[q * 4 + 1], ob[q * 4 + 2], ob[q * 4 + 3]);
    float4* m4 = reinterpret_cast<float4*>(out + NPROP * 5) + tid * 2;
    m4[0] = make_float4(om[0], om[1], om[2], om[3]);
    m4[1] = make_float4(om[4], om[5], om[6], om[7]);
}

extern "C" void kernel_launch(void* const* d_in, const int* in_sizes, int n_in,
                              void* d_out, int out_size, void* d_ws, size_t ws_size,
                              hipStream_t stream) {
    const float* boxes  = (const float*)d_in[0];
    const float* scores = (const float*)d_in[1];
    const float* img    = (const float*)d_in[2];
    char* ws = (char*)d_ws;
    int*    pref_ex  = (int*)(ws + 0);         // 32 KiB
    int*    pref_mut = (int*)(ws + 32768);     // 32 KiB
    int*    tmp_idx  = (int*)(ws + 65536);     // 32 KiB
    float*  srt_sv   = (float*)(ws + 98304);   // 32 KiB
    float4* srt_box  = (float4*)(ws + 131072); // 128 KiB
    float4* cbox     = (float4*)(ws + 262144); // 128 KiB
    int*    crank    = (int*)(ws + 393216);    // 32 KiB
    int*    meta     = (int*)(ws + 425984);    // 1 KiB (padded)
    u64*    mask     = (u64*)(ws + 427008);    // V*W*8 B (realistic ~200 KiB)
    float* out = (float*)d_out;

    k_scanhist<<<1, NT, 0, stream>>>(scores, pref_ex, pref_mut);
    k_scatter<<<32, 256, 0, stream>>>(scores, pref_mut, tmp_idx);
    k_rank<<<32, 256, 0, stream>>>(scores, boxes, img, tmp_idx, pref_ex, pref_mut,
                                   srt_box, srt_sv);
    k_compact<<<1, NT, 0, stream>>>(srt_box, srt_sv, cbox, crank, meta);
    k_mask<<<256, 256, 0, stream>>>(cbox, meta, mask);
    k_resolve_out<<<1, NT, 0, stream>>>(mask, meta, srt_box, srt_sv, crank, out);
}

// Round 11
// 73.565 us; speedup vs baseline: 1.4960x; 1.1155x over previous
//
#include <hip/hip_runtime.h>

#define NPROP 8192
#define NT 1024
#define NTR 256
#define SLABW 27   // slab stride in words (odd -> spread LDS banks; const divisor)
typedef unsigned long long u64;

__device__ __forceinline__ int bucket_of(float s) {
    int b = (int)(s * 8192.0f);   // exact: *2^13 is an exponent shift
    return b < 0 ? 0 : (b > NPROP - 1 ? NPROP - 1 : b);
}

__device__ __forceinline__ bool iou_gt_thr(float4 a, float4 b) {
    float areaA = (a.z - a.x) * (a.w - a.y);
    float areaB = (b.z - b.x) * (b.w - b.y);
    float lx = fmaxf(a.x, b.x), ly = fmaxf(a.y, b.y);
    float rx = fminf(a.z, b.z), ry = fminf(a.w, b.w);
    float w = fmaxf(rx - lx, 0.0f), h = fmaxf(ry - ly, 0.0f);
    float inter = w * h;
    float uni = areaA + areaB - inter;
    float iou = inter / fmaxf(uni, 1e-6f);
    return iou > 0.3f;
}

// K1: LDS histogram + scan + scatter (1 block; allocator stays in LDS)
__global__ __launch_bounds__(NT)
void k_sort1(const float* __restrict__ scores, int* __restrict__ pref_ex,
             int* __restrict__ tmp_idx) {
    __shared__ int hist[NPROP];   // 32 KiB: counts -> allocator
    __shared__ int wsum[16], wexcl[16];
    const int tid = threadIdx.x, lane = tid & 63, wave = tid >> 6;
    #pragma unroll
    for (int u = 0; u < 8; u++) hist[tid * 8 + u] = 0;
    __syncthreads();
    const float4* s4 = reinterpret_cast<const float4*>(scores);
    float4 sa = s4[tid * 2], sb = s4[tid * 2 + 1];
    float ss[8] = {sa.x, sa.y, sa.z, sa.w, sb.x, sb.y, sb.z, sb.w};
    int bk[8];
    #pragma unroll
    for (int u = 0; u < 8; u++) { bk[u] = bucket_of(ss[u]); atomicAdd(&hist[bk[u]], 1); }
    __syncthreads();
    int h[8]; int tot = 0;
    #pragma unroll
    for (int u = 0; u < 8; u++) { h[u] = hist[tid * 8 + u]; tot += h[u]; }
    int incl = tot;
    #pragma unroll
    for (int off = 1; off < 64; off <<= 1) {
        int n = __shfl_up(incl, off, 64);
        if (lane >= off) incl += n;
    }
    if (lane == 63) wsum[wave] = incl;
    __syncthreads();
    if (tid == 0) {
        int acc = 0;
        #pragma unroll
        for (int w = 0; w < 16; w++) { int t = wsum[w]; wexcl[w] = acc; acc += t; }
    }
    __syncthreads();
    int run = wexcl[wave] + (incl - tot);
    int run2 = run;
    #pragma unroll
    for (int u = 0; u < 8; u++) { pref_ex[tid * 8 + u] = run; run += h[u]; }
    // overwrite hist as allocator (all scan reads are done; last barrier passed)
    #pragma unroll
    for (int u = 0; u < 8; u++) { hist[tid * 8 + u] = run2; run2 += h[u]; }
    __syncthreads();
    #pragma unroll
    for (int u = 0; u < 8; u++) {
        int slot = atomicAdd(&hist[bk[u]], 1);
        tmp_idx[slot] = tid * 8 + u;
    }
}

// K2: exact stable rank via in-bucket counting + validity (bucket end = pref_ex[b+1])
__global__ void k_rank(const float* __restrict__ scores, const float* __restrict__ boxes,
                       const float* __restrict__ img,
                       const int* __restrict__ tmp_idx, const int* __restrict__ pref_ex,
                       float4* __restrict__ srt_box, float* __restrict__ srt_sv) {
    int p = blockIdx.x * blockDim.x + threadIdx.x;
    if (p >= NPROP) return;
    int i = tmp_idx[p];
    float s = scores[i];
    u64 key = ((u64)__float_as_uint(s) << 32) | (u64)(unsigned)(NPROP - 1 - i);
    int b = bucket_of(s);
    int lo = pref_ex[b];
    int hi = (b < NPROP - 1) ? pref_ex[b + 1] : NPROP;
    int cnt = 0;
    for (int q = lo; q < hi; q++) {
        int j = tmp_idx[q];
        u64 kj = ((u64)__float_as_uint(scores[j]) << 32) | (u64)(unsigned)(NPROP - 1 - j);
        cnt += (kj < key) ? 1 : 0;
    }
    int rank = NPROP - 1 - (lo + cnt);
    float4 bx = reinterpret_cast<const float4*>(boxes)[i];
    float ix1 = img[0], iy1 = img[1], ix2 = img[2], iy2 = img[3];
    float img_area = (ix2 - ix1) * (iy2 - iy1);
    float w = bx.z - bx.x, hh = bx.w - bx.y;
    float ratio = w / (hh + 1e-12f);
    bool vs = (ratio > 0.25f) && (ratio < 4.0f);
    float lx = fmaxf(ix1, bx.x), ly = fmaxf(iy1, bx.y);
    float rx = fminf(ix2, bx.z), ry = fminf(iy2, bx.w);
    float iw = fmaxf(rx - lx, 0.0f), ih = fmaxf(ry - ly, 0.0f);
    float iof = (iw * ih) / fmaxf(img_area, 1e-6f);
    bool vf = vs && (iof > 0.01f) && (s > 0.85f);
    srt_box[rank] = bx;
    srt_sv[rank] = __uint_as_float(__float_as_uint(s) | (vf ? 0x80000000u : 0u));
}

// K3: compact valid subset + V/W meta
__global__ __launch_bounds__(NT)
void k_compact(const float4* __restrict__ srt_box, const float* __restrict__ srt_sv,
               float4* __restrict__ cbox, int* __restrict__ crank,
               int* __restrict__ meta) {
    __shared__ int wsum[16], wexcl[16];
    const int tid = threadIdx.x, lane = tid & 63, wave = tid >> 6;
    bool vf[8]; int tot = 0;
    float4 bx[8];
    #pragma unroll
    for (int u = 0; u < 8; u++) {
        int p = tid * 8 + u;
        bx[u] = srt_box[p];
        vf[u] = (__float_as_uint(srt_sv[p]) >> 31) != 0;
        tot += vf[u] ? 1 : 0;
    }
    int incl = tot;
    #pragma unroll
    for (int off = 1; off < 64; off <<= 1) {
        int n = __shfl_up(incl, off, 64);
        if (lane >= off) incl += n;
    }
    if (lane == 63) wsum[wave] = incl;
    __syncthreads();
    if (tid == 0) {
        int acc = 0;
        #pragma unroll
        for (int w = 0; w < 16; w++) { int t = wsum[w]; wexcl[w] = acc; acc += t; }
        int V = acc == 0 ? 1 : acc;
        meta[0] = V;
        meta[1] = (V + 63) >> 6;
        meta[2] = acc;              // raw count (0 => fallback)
    }
    __syncthreads();
    int base = wexcl[wave] + (incl - tot);
    #pragma unroll
    for (int u = 0; u < 8; u++) {
        int p = tid * 8 + u;
        if (vf[u]) { crank[p] = base; cbox[base] = bx[u]; base++; }
        else crank[p] = -1;
    }
    if (meta[2] == 0 && tid == 0) { crank[0] = 0; cbox[0] = srt_box[0]; }
}

// K4: suppression mask matrix — wave per row, lane per column
__global__ __launch_bounds__(256)
void k_mask(const float4* __restrict__ cbox, const int* __restrict__ meta,
            u64* __restrict__ mask) {
    const int V = meta[0], W = meta[1];
    const int lane = threadIdx.x & 63;
    int gw = blockIdx.x * 4 + (threadIdx.x >> 6);
    for (int r = gw; r < V; r += 1024) {
        float4 br = cbox[r];
        for (int w = (r >> 6); w < W; w++) {
            int col = w * 64 + lane;
            bool ok = (col < V) && (col > r) && iou_gt_thr(br, cbox[col]);
            u64 bal = __ballot(ok);
            if (lane == 0) mask[(u64)r * W + w] = bal;
        }
    }
}

// K5: greedy resolve — scalar kept-only chain + flat LDS slab double-buffer
__global__ __launch_bounds__(NTR)
void k_resolve(const u64* __restrict__ mask, const int* __restrict__ meta,
               u64* __restrict__ remG) {
    __shared__ u64 rem[NPROP / 64];        // 1 KiB
    __shared__ u64 slab[2][64 * SLABW];    // 27.6 KiB
    const int V = meta[0], W = meta[1];
    const int tid = threadIdx.x, lane = tid & 63, wave = tid >> 6;

    for (int w = tid; w < NPROP / 64; w += NTR) {
        int b0 = w * 64; u64 m;
        if (b0 >= V) m = ~0ull;
        else if (b0 + 64 <= V) m = 0ull;
        else m = (~0ull) << (V - b0);
        rem[w] = m;
    }
    // prologue: slab for block 0 (rows 0..63, word-cols [0, min(W,SLABW)))
    #pragma unroll
    for (int k = 0; k < 7; k++) {
        int idx = tid + k * NTR;
        if (idx < 64 * SLABW) {
            int rl = idx / SLABW, off = idx - rl * SLABW;   // const-divisor
            u64 v = 0;
            if (off < W) v = mask[(u64)rl * W + off];
            slab[0][idx] = v;
        }
    }
    __syncthreads();

    int cur = 0;
    for (int b = 0; b < W; b++) {
        const int rb0 = b * 64;
        const int B = b + 1;
        // 1) issue prefetch of block b+1 into registers
        u64 pf[7]; bool pv[7];
        #pragma unroll
        for (int k = 0; k < 7; k++) {
            pv[k] = false; pf[k] = 0;
            int idx = tid + k * NTR;
            if (B < W && idx < 64 * SLABW) {
                int rl = idx / SLABW, off = idx - rl * SLABW;
                pv[k] = true;
                if (B + off < W)
                    pf[k] = mask[(u64)(B * 64 + rl) * W + (B + off)];
            }
        }
        // 2) chain on wave 0: scalar r, iterate KEPT rows only via ctz+readlane
        if (tid < 64) {
            u64 d = slab[cur][lane * SLABW];   // diag word of row rb0+lane
            int dlo = (int)(unsigned)(d & 0xffffffffull);
            int dhi = (int)(unsigned)(d >> 32);
            u64 r0 = rem[b];
            unsigned rl_ = (unsigned)__builtin_amdgcn_readfirstlane((int)(unsigned)(r0 & 0xffffffffull));
            unsigned rh_ = (unsigned)__builtin_amdgcn_readfirstlane((int)(unsigned)(r0 >> 32));
            u64 r = ((u64)rh_ << 32) | (u64)rl_;
            u64 avail = ~r;                    // not-removed candidates (pad bits preset)
            while (avail) {
                int i = (int)__builtin_ctzll(avail);          // lowest candidate -> KEPT
                unsigned xl = (unsigned)__builtin_amdgcn_readlane(dlo, i);
                unsigned xh = (unsigned)__builtin_amdgcn_readlane(dhi, i);
                u64 di = ((u64)xh << 32) | (u64)xl;           // its in-word suppression
                r |= di;
                u64 x = avail & ~di;                          // drop suppressed
                avail = x & (x - 1);                          // drop row i itself
            }
            if (lane == 0) rem[b] = r;
        }
        __syncthreads();
        // 3) apply: per-wave masked OR of its 16 rows' slab words, 1 atomic/lane
        const int cnt = min(W - b, SLABW);
        u64 keptm = ~rem[b];
        if (lane + 1 < cnt) {
            u64 acc = 0;
            #pragma unroll
            for (int t = 0; t < 16; t++) {
                int rl = wave * 16 + t;
                u64 wm = ((rb0 + rl) < V && ((keptm >> rl) & 1ull)) ? ~0ull : 0ull;
                acc |= slab[cur][rl * SLABW + 1 + lane] & wm;
            }
            if (acc) atomicOr((unsigned long long*)&rem[b + 1 + lane], acc);
        }
        // beyond-slab fallback (only if W-b > SLABW)
        if (W - b > SLABW) {
            for (int t = 0; t < 16; t++) {
                int rl = wave * 16 + t; int row = rb0 + rl;
                if (row < V && ((keptm >> rl) & 1ull)) {
                    for (int w2 = b + SLABW + lane; w2 < W; w2 += 64) {
                        u64 m = mask[(u64)row * W + w2];
                        if (m) atomicOr((unsigned long long*)&rem[w2], m);
                    }
                }
            }
        }
        // 4) land prefetch into the other buffer
        #pragma unroll
        for (int k = 0; k < 7; k++)
            if (pv[k]) slab[cur ^ 1][tid + k * NTR] = pf[k];
        __syncthreads();
        cur ^= 1;
    }

    for (int w = tid; w < NPROP / 64; w += NTR) remG[w] = rem[w];
}

// K6: final output [N,5]*keep + keep mask, vectorized float4 stores (4 CUs)
__global__ __launch_bounds__(256)
void k_out(const float4* __restrict__ srt_box, const float* __restrict__ srt_sv,
           const int* __restrict__ crank, const u64* __restrict__ remG,
           float* __restrict__ out) {
    int tid = blockIdx.x * 256 + threadIdx.x;   // 0..1023, 8 positions each
    float ob[40]; float om[8];
    #pragma unroll
    for (int u = 0; u < 8; u++) {
        int p = tid * 8 + u;
        float4 b = srt_box[p];
        unsigned svb = __float_as_uint(srt_sv[p]);
        float s = __uint_as_float(svb & 0x7fffffffu);
        int k = crank[p];
        bool keep = (k >= 0) && !((remG[k >> 6] >> (k & 63)) & 1ull);
        float m = keep ? 1.0f : 0.0f;
        ob[u * 5 + 0] = b.x * m;
        ob[u * 5 + 1] = b.y * m;
        ob[u * 5 + 2] = b.z * m;
        ob[u * 5 + 3] = b.w * m;
        ob[u * 5 + 4] = s * m;
        om[u] = m;
    }
    float4* o4 = reinterpret_cast<float4*>(out) + tid * 10;
    #pragma unroll
    for (int q = 0; q < 10; q++)
        o4[q] = make_float4(ob[q * 4 + 0], ob[q * 4 + 1], ob[q * 4 + 2], ob[q * 4 + 3]);
    float4* m4 = reinterpret_cast<float4*>(out + NPROP * 5) + tid * 2;
    m4[0] = make_float4(om[0], om[1], om[2], om[3]);
    m4[1] = make_float4(om[4], om[5], om[6], om[7]);
}

extern "C" void kernel_launch(void* const* d_in, const int* in_sizes, int n_in,
                              void* d_out, int out_size, void* d_ws, size_t ws_size,
                              hipStream_t stream) {
    const float* boxes  = (const float*)d_in[0];
    const float* scores = (const float*)d_in[1];
    const float* img    = (const float*)d_in[2];
    char* ws = (char*)d_ws;
    int*    pref_ex  = (int*)(ws + 0);         // 32 KiB
    int*    tmp_idx  = (int*)(ws + 32768);     // 32 KiB
    float*  srt_sv   = (float*)(ws + 65536);   // 32 KiB
    float4* srt_box  = (float4*)(ws + 98304);  // 128 KiB
    float4* cbox     = (float4*)(ws + 229376); // 128 KiB
    int*    crank    = (int*)(ws + 360448);    // 32 KiB
    int*    meta     = (int*)(ws + 393216);    // 1 KiB (padded)
    u64*    remG     = (u64*)(ws + 394240);    // 1 KiB
    u64*    mask     = (u64*)(ws + 395264);    // V*W*8 B (realistic ~300 KiB)
    float* out = (float*)d_out;

    k_sort1<<<1, NT, 0, stream>>>(scores, pref_ex, tmp_idx);
    k_rank<<<32, 256, 0, stream>>>(scores, boxes, img, tmp_idx, pref_ex,
                                   srt_box, srt_sv);
    k_compact<<<1, NT, 0, stream>>>(srt_box, srt_sv, cbox, crank, meta);
    k_mask<<<256, 256, 0, stream>>>(cbox, meta, mask);
    k_resolve<<<1, NTR, 0, stream>>>(mask, meta, remG);
    k_out<<<4, 256, 0, stream>>>(srt_box, srt_sv, crank, remG, out);
}